// Round 6
// baseline (273.179 us; speedup 1.0000x reference)
//
#include <hip/hip_runtime.h>
#include <math.h>

#define BB 32
#define MM 10
#define NNODES 1010
#define DD 128
#define RPB 32                          // node rows per tile in k_nodes
#define NG 32                           // ceil(1010/32)

// ---------------------------------------------------------------------------
// k_front (49 blocks x 512 threads), one launch, three independent roles:
//   blocks 0..31  : full agent pipeline for batch b = blockIdx.x
//   blocks 32..47 : wnT[k][d] = W_final[d][k]   (transpose for k_nodes)
//   block  48     : v_pref[d] = dot(W_final[d,128:256], W_pref)
// ---------------------------------------------------------------------------
__global__ __launch_bounds__(512) void k_front(
    const float* __restrict__ locs,      // (B, 1010, 2)
    const float* __restrict__ capacity,  // (B, 10)
    const float* __restrict__ speed,     // (B, 10)
    const float* __restrict__ W_depot,   // (128, 2)
    const float* __restrict__ W_posproj, // (128, 128)
    const float* __restrict__ alpha,     // (1,)
    const float* __restrict__ W_agents,  // (128, 4)
    const float* __restrict__ W_da,      // (128, 256)
    const float* __restrict__ W_pref,    // (128, 1)
    const float* __restrict__ W_final,   // (128, 384)
    float* __restrict__ out_nodes,       // (B, 1010, 128)
    float* __restrict__ ws_daWd,         // (B, 10, 128)
    float* __restrict__ ws_wnT,          // (128, 128)
    float* __restrict__ ws_vpref)        // (128,)
{
    const int bk = blockIdx.x;
    const int t = threadIdx.x;

    if (bk < BB) {
        const int b = bk;
        const int d = t >> 2;        // 0..127
        const int q = t & 3;         // K-quarter

        __shared__ float pe_s[MM][DD];     // 5 KB
        __shared__ float cat_s[2 * DD];    // [dep | ag]
        __shared__ float da_s[DD];

        for (int idx = t; idx < MM * DD; idx += 512) {
            const int m = idx >> 7;
            const int k = idx & (DD - 1);
            const int i = k >> 1;
            const float div = expf((float)(2 * i) * (-logf(10000.0f) / (float)DD));
            const float ang = (float)m * div;
            pe_s[m][k] = (k & 1) ? cosf(ang) : sinf(ang);
        }

        float4 wpp[8], wfd[8], wda[16];
        {
            const float4* p = (const float4*)(W_posproj + (size_t)d * DD + q * 32);
            #pragma unroll
            for (int i = 0; i < 8; ++i) wpp[i] = p[i];
        }
        {
            const float4* p = (const float4*)(W_da + (size_t)d * 256 + q * 64);
            #pragma unroll
            for (int i = 0; i < 16; ++i) wda[i] = p[i];
        }
        {
            const float4* p = (const float4*)(W_final + (size_t)d * 384 + 256 + q * 32);
            #pragma unroll
            for (int i = 0; i < 8; ++i) wfd[i] = p[i];
        }
        const float wd0 = W_depot[d * 2 + 0], wd1 = W_depot[d * 2 + 1];
        const float wa0 = W_agents[d * 4 + 0], wa1 = W_agents[d * 4 + 1];
        const float wa2 = W_agents[d * 4 + 2], wa3 = W_agents[d * 4 + 3];
        const float al = alpha[0];
        __syncthreads();

        for (int m = 0; m < MM; ++m) {
            float pp = 0.0f;
            {
                const float4* pe4 = (const float4*)(&pe_s[m][q * 32]);
                #pragma unroll
                for (int i = 0; i < 8; ++i) {
                    const float4 w = wpp[i], x = pe4[i];
                    pp = fmaf(w.x, x.x, fmaf(w.y, x.y, fmaf(w.z, x.z, fmaf(w.w, x.w, pp))));
                }
            }
            pp += __shfl_xor(pp, 1, 4);
            pp += __shfl_xor(pp, 2, 4);

            if (q == 0) {
                const float lx = locs[((size_t)b * NNODES + m) * 2 + 0];
                const float ly = locs[((size_t)b * NNODES + m) * 2 + 1];
                const float dep = fmaf(lx, wd0, fmaf(ly, wd1, al * pp));
                const float cap = capacity[b * MM + m] * (1.0f / 40.0f);
                const float spd = speed[b * MM + m];
                const float ag = fmaf(lx, wa0, fmaf(ly, wa1,
                                 fmaf(cap, wa2, spd * wa3)));
                out_nodes[((size_t)b * NNODES + m) * DD + d] = ag;
                cat_s[d] = dep;
                cat_s[DD + d] = ag;
            }
            __syncthreads();

            float da = 0.0f;
            {
                const float4* c4 = (const float4*)(cat_s + q * 64);
                #pragma unroll
                for (int i = 0; i < 16; ++i) {
                    const float4 w = wda[i], x = c4[i];
                    da = fmaf(w.x, x.x, fmaf(w.y, x.y, fmaf(w.z, x.z, fmaf(w.w, x.w, da))));
                }
            }
            da += __shfl_xor(da, 1, 4);
            da += __shfl_xor(da, 2, 4);
            if (q == 0) da_s[d] = da;
            __syncthreads();

            float dw = 0.0f;
            {
                const float4* c4 = (const float4*)(da_s + q * 32);
                #pragma unroll
                for (int i = 0; i < 8; ++i) {
                    const float4 w = wfd[i], x = c4[i];
                    dw = fmaf(w.x, x.x, fmaf(w.y, x.y, fmaf(w.z, x.z, fmaf(w.w, x.w, dw))));
                }
            }
            dw += __shfl_xor(dw, 1, 4);
            dw += __shfl_xor(dw, 2, 4);
            if (q == 0)
                ws_daWd[(b * MM + m) * DD + d] = dw;
            __syncthreads();
        }
    } else if (bk < 48) {
        const int d = t & (DD - 1);
        const int j = t >> 7;            // 0..3
        const int k0 = (bk - 32) * 8;
        #pragma unroll
        for (int l = 0; l < 2; ++l) {
            const int k = k0 + j * 2 + l;
            ws_wnT[k * DD + d] = W_final[(size_t)d * 384 + k];
        }
    } else {
        if (t < DD) {
            const int d = t;
            float vp = 0.0f;
            const float4* w = (const float4*)(W_final + (size_t)d * 384 + DD);
            const float4* p = (const float4*)W_pref;
            #pragma unroll
            for (int k4 = 0; k4 < 32; ++k4) {
                const float4 a = w[k4], bb = p[k4];
                vp = fmaf(a.x, bb.x, fmaf(a.y, bb.y, fmaf(a.z, bb.z, fmaf(a.w, bb.w, vp))));
            }
            ws_vpref[d] = vp;
        }
    }
}

// ---------------------------------------------------------------------------
// k_nodes: R3's proven geometry (RPB=32, 8 rows/wave). Client embeddings ->
// out_nodes + LDS; gemv vs wnT -> ws_nwn. Regular cached stores only.
// ---------------------------------------------------------------------------
__global__ __launch_bounds__(256) void k_nodes(
    const float* __restrict__ locs,      // (B, 1010, 2)
    const float* __restrict__ demand,    // (B, 1, 1010)
    const float* __restrict__ W_clients, // (128, 5)
    const float* __restrict__ wnT,       // (128, 128)
    float* __restrict__ out_nodes,       // (B, 1010, 128)
    float* __restrict__ ws_nwn)          // (B, 1010, 128)
{
    const int g = blockIdx.x;
    const int b = blockIdx.y;
    const int t = threadIdx.x;
    const int n0 = g * RPB;

    __shared__ float rows[RPB][DD];      // 16 KB
    __shared__ float feat[RPB][5];

    if (t < RPB) {
        const int node = n0 + t;
        if (node < NNODES && node >= MM) {
            const float cx = locs[((size_t)b * NNODES + node) * 2 + 0];
            const float cy = locs[((size_t)b * NNODES + node) * 2 + 1];
            const float d0x = locs[((size_t)b * NNODES + 0) * 2 + 0];
            const float d0y = locs[((size_t)b * NNODES + 0) * 2 + 1];
            const float dx = cx - d0x;
            const float dy = cy - d0y;
            feat[t][0] = cx;
            feat[t][1] = cy;
            feat[t][2] = demand[(size_t)b * NNODES + node] * (1.0f / 40.0f);
            feat[t][3] = sqrtf(fmaf(dx, dx, dy * dy));
            feat[t][4] = atan2f(dy, dx);
        }
    }
    __syncthreads();

    // phase A
    {
        const int d = t & (DD - 1);
        const int h = t >> 7;
        const float wc0 = W_clients[d * 5 + 0];
        const float wc1 = W_clients[d * 5 + 1];
        const float wc2 = W_clients[d * 5 + 2];
        const float wc3 = W_clients[d * 5 + 3];
        const float wc4 = W_clients[d * 5 + 4];
        #pragma unroll
        for (int i = 0; i < RPB / 2; ++i) {
            const int r = h * (RPB / 2) + i;
            const int node = n0 + r;
            float val = 0.0f;
            if (node < NNODES) {
                if (node < MM) {
                    val = out_nodes[((size_t)b * NNODES + node) * DD + d];
                } else {
                    val = fmaf(feat[r][0], wc0,
                          fmaf(feat[r][1], wc1,
                          fmaf(feat[r][2], wc2,
                          fmaf(feat[r][3], wc3,
                               feat[r][4] * wc4))));
                    out_nodes[((size_t)b * NNODES + node) * DD + d] = val;
                }
            }
            rows[r][d] = val;
        }
    }
    __syncthreads();

    // phase B: (c = t&31 -> cols 4c..4c+3, s = t>>5 -> rows 4s..4s+3)
    const int c = t & 31;
    const int s = t >> 5;
    const int col = c * 4;
    float4 acc[4];
    #pragma unroll
    for (int j = 0; j < 4; ++j) acc[j] = make_float4(0.f, 0.f, 0.f, 0.f);

    {
        const float* wt = wnT + col;
        #pragma unroll 2
        for (int k4 = 0; k4 < DD / 4; ++k4) {
            const float4 w0 = *(const float4*)(wt + (size_t)(k4 * 4 + 0) * DD);
            const float4 w1 = *(const float4*)(wt + (size_t)(k4 * 4 + 1) * DD);
            const float4 w2 = *(const float4*)(wt + (size_t)(k4 * 4 + 2) * DD);
            const float4 w3 = *(const float4*)(wt + (size_t)(k4 * 4 + 3) * DD);
            #pragma unroll
            for (int j = 0; j < 4; ++j) {
                const float4 x = *(const float4*)&rows[s * 4 + j][k4 * 4];
                acc[j].x = fmaf(x.x, w0.x, fmaf(x.y, w1.x,
                           fmaf(x.z, w2.x, fmaf(x.w, w3.x, acc[j].x))));
                acc[j].y = fmaf(x.x, w0.y, fmaf(x.y, w1.y,
                           fmaf(x.z, w2.y, fmaf(x.w, w3.y, acc[j].y))));
                acc[j].z = fmaf(x.x, w0.z, fmaf(x.y, w1.z,
                           fmaf(x.z, w2.z, fmaf(x.w, w3.z, acc[j].z))));
                acc[j].w = fmaf(x.x, w0.w, fmaf(x.y, w1.w,
                           fmaf(x.z, w2.w, fmaf(x.w, w3.w, acc[j].w))));
            }
        }
    }

    #pragma unroll
    for (int j = 0; j < 4; ++j) {
        const int node = n0 + s * 4 + j;
        if (node < NNODES)
            *(float4*)(ws_nwn + ((size_t)b * NNODES + node) * DD + col) = acc[j];
    }
}

// ---------------------------------------------------------------------------
// k_expand: pure streaming expansion, fill-like. grid (8, 320): blockIdx.y
// = (b,mm) panel, blockIdx.x = 128-node chunk. Regular cached float4 stores.
//   out[b,mm,node,:] = nwn[b,node,:] + pref[b,mm,node]*vp[:] + daWd[b,mm,:]
// ---------------------------------------------------------------------------
__global__ __launch_bounds__(256) void k_expand(
    const float* __restrict__ pref,      // (B, 10, 1010)
    const float* __restrict__ ws_nwn,    // (B, 1010, 128)
    const float* __restrict__ ws_daWd,   // (B, 10, 128)
    const float* __restrict__ ws_vpref,  // (128,)
    float* __restrict__ out_comb)        // (B, 10, 1010, 128)
{
    const int p = blockIdx.y;            // 0..319 : (b, mm)
    const int b = p / MM;
    const int mm = p - b * MM;
    const int t = threadIdx.x;
    const int col = (t & 31) * 4;
    const int n0 = blockIdx.x * 128 + (t >> 5);   // this thread's first node

    const float4 vp = *(const float4*)(ws_vpref + col);
    const float4 dw = *(const float4*)(ws_daWd + (size_t)p * DD + col);
    const float* prf = pref + (size_t)p * NNODES;
    const float* nwb = ws_nwn + (size_t)b * NNODES * DD;
    float* outb = out_comb + (size_t)p * NNODES * DD;

    #pragma unroll 4
    for (int node = n0; node < min(blockIdx.x * 128 + 128, NNODES); node += 8) {
        const float pr = prf[node];
        const float4 nw = *(const float4*)(nwb + (size_t)node * DD + col);
        float4 o;
        o.x = fmaf(pr, vp.x, nw.x + dw.x);
        o.y = fmaf(pr, vp.y, nw.y + dw.y);
        o.z = fmaf(pr, vp.z, nw.z + dw.z);
        o.w = fmaf(pr, vp.w, nw.w + dw.w);
        *(float4*)(outb + (size_t)node * DD + col) = o;
    }
}

extern "C" void kernel_launch(void* const* d_in, const int* in_sizes, int n_in,
                              void* d_out, int out_size, void* d_ws, size_t ws_size,
                              hipStream_t stream) {
    const float* locs        = (const float*)d_in[0];
    const float* capacity    = (const float*)d_in[1];
    const float* speed       = (const float*)d_in[2];
    const float* demand      = (const float*)d_in[3];
    const float* agents_pref = (const float*)d_in[4];
    // d_in[5] action_mask: only its shape is used by the reference
    const float* W_depot     = (const float*)d_in[6];
    const float* W_posproj   = (const float*)d_in[7];
    const float* alpha       = (const float*)d_in[8];
    const float* W_agents    = (const float*)d_in[9];
    const float* W_da        = (const float*)d_in[10];
    const float* W_clients   = (const float*)d_in[11];
    const float* W_pref      = (const float*)d_in[12];
    const float* W_final     = (const float*)d_in[13];

    float* out_nodes = (float*)d_out;                         // 32*1010*128
    float* out_comb  = out_nodes + (size_t)BB * NNODES * DD;  // 32*10*1010*128

    float* ws_daWd  = (float*)d_ws;                     // 40960 floats
    float* ws_vpref = ws_daWd + BB * MM * DD;           // 128
    float* ws_wnT   = ws_vpref + DD;                    // 16384
    float* ws_nwn   = ws_wnT + DD * DD;                 // 32*1010*128

    k_front<<<dim3(49), 512, 0, stream>>>(
        locs, capacity, speed, W_depot, W_posproj, alpha, W_agents,
        W_da, W_pref, W_final, out_nodes, ws_daWd, ws_wnT, ws_vpref);

    k_nodes<<<dim3(NG, BB), 256, 0, stream>>>(
        locs, demand, W_clients, ws_wnT, out_nodes, ws_nwn);

    k_expand<<<dim3(8, BB * MM), 256, 0, stream>>>(
        agents_pref, ws_nwn, ws_daWd, ws_vpref, out_comb);
}

// Round 8
// 250.024 us; speedup vs baseline: 1.0926x; 1.0926x over previous
//
#include <hip/hip_runtime.h>
#include <math.h>

#define BB 32
#define MM 10
#define NNODES 1010
#define DD 128
#define RPB 32                          // node rows per tile in k_main
#define NG 32                           // ceil(1010/32)

// ---------------------------------------------------------------------------
// k_front (49 blocks x 512 threads), ONE launch, three independent roles:
//   blocks 0..31  : agent pipeline for batch b, ALL m in parallel between
//                   just 2 barriers. thread t -> (d = t>>2, q = t&3);
//                   weight ROW q-slices in registers (contiguous loads),
//                   K-partials reduced with __shfl_xor over the 4-lane group.
//   blocks 32..47 : wnT[k][d] = W_final[d][k]   (transpose for k_main)
//   block  48     : v_pref[d] = dot(W_final[d,128:256], W_pref)
// ---------------------------------------------------------------------------
__global__ __launch_bounds__(512) void k_front(
    const float* __restrict__ locs,      // (B, 1010, 2)
    const float* __restrict__ capacity,  // (B, 10)
    const float* __restrict__ speed,     // (B, 10)
    const float* __restrict__ W_depot,   // (128, 2)
    const float* __restrict__ W_posproj, // (128, 128)
    const float* __restrict__ alpha,     // (1,)
    const float* __restrict__ W_agents,  // (128, 4)
    const float* __restrict__ W_da,      // (128, 256)
    const float* __restrict__ W_pref,    // (128, 1)
    const float* __restrict__ W_final,   // (128, 384)
    float* __restrict__ out_nodes,       // (B, 1010, 128)
    float* __restrict__ ws_daWd,         // (B, 10, 128)
    float* __restrict__ ws_wnT,          // (128, 128)
    float* __restrict__ ws_vpref)        // (128,)
{
    const int bk = blockIdx.x;
    const int t = threadIdx.x;

    if (bk < BB) {
        const int b = bk;
        const int d = t >> 2;        // 0..127
        const int q = t & 3;         // K-quarter

        __shared__ float pe_s[MM][DD];       // 5 KB
        __shared__ float cat_s[MM][2 * DD];  // 10 KB  [dep | ag] per m
        __shared__ float da_s[MM][DD];       // 5 KB

        // positional encodings for all (m, k)
        for (int idx = t; idx < MM * DD; idx += 512) {
            const int m = idx >> 7;
            const int k = idx & (DD - 1);
            const int i = k >> 1;
            const float div = expf((float)(2 * i) * (-logf(10000.0f) / (float)DD));
            const float ang = (float)m * div;
            pe_s[m][k] = (k & 1) ? cosf(ang) : sinf(ang);
        }

        // weight ROW q-slices for this (d, q) -> registers (contiguous loads)
        float4 wpp[8], wfd[8], wda[16];
        {
            const float4* p = (const float4*)(W_posproj + (size_t)d * DD + q * 32);
            #pragma unroll
            for (int i = 0; i < 8; ++i) wpp[i] = p[i];
        }
        {
            const float4* p = (const float4*)(W_da + (size_t)d * 256 + q * 64);
            #pragma unroll
            for (int i = 0; i < 16; ++i) wda[i] = p[i];
        }
        {
            const float4* p = (const float4*)(W_final + (size_t)d * 384 + 256 + q * 32);
            #pragma unroll
            for (int i = 0; i < 8; ++i) wfd[i] = p[i];
        }
        const float wd0 = W_depot[d * 2 + 0], wd1 = W_depot[d * 2 + 1];
        const float wa0 = W_agents[d * 4 + 0], wa1 = W_agents[d * 4 + 1];
        const float wa2 = W_agents[d * 4 + 2], wa3 = W_agents[d * 4 + 3];
        const float al = alpha[0];
        __syncthreads();                     // pe_s ready

        // ---- all m: peproj partial -> dep/ag -> cat_s (no barriers) ----
        #pragma unroll
        for (int m = 0; m < MM; ++m) {
            float pp = 0.0f;
            const float4* pe4 = (const float4*)(&pe_s[m][q * 32]);
            #pragma unroll
            for (int i = 0; i < 8; ++i) {
                const float4 w = wpp[i], x = pe4[i];
                pp = fmaf(w.x, x.x, fmaf(w.y, x.y, fmaf(w.z, x.z, fmaf(w.w, x.w, pp))));
            }
            pp += __shfl_xor(pp, 1, 4);
            pp += __shfl_xor(pp, 2, 4);

            if (q == 0) {
                const float lx = locs[((size_t)b * NNODES + m) * 2 + 0];
                const float ly = locs[((size_t)b * NNODES + m) * 2 + 1];
                const float dep = fmaf(lx, wd0, fmaf(ly, wd1, al * pp));
                const float cap = capacity[b * MM + m] * (1.0f / 40.0f);
                const float spd = speed[b * MM + m];
                const float ag = fmaf(lx, wa0, fmaf(ly, wa1,
                                 fmaf(cap, wa2, spd * wa3)));
                out_nodes[((size_t)b * NNODES + m) * DD + d] = ag;
                cat_s[m][d] = dep;
                cat_s[m][DD + d] = ag;
            }
        }
        __syncthreads();                     // cat_s ready

        // ---- all m: da partial (k in [q*64, q*64+64)) ----
        #pragma unroll
        for (int m = 0; m < MM; ++m) {
            float da = 0.0f;
            const float4* c4 = (const float4*)(&cat_s[m][q * 64]);
            #pragma unroll
            for (int i = 0; i < 16; ++i) {
                const float4 w = wda[i], x = c4[i];
                da = fmaf(w.x, x.x, fmaf(w.y, x.y, fmaf(w.z, x.z, fmaf(w.w, x.w, da))));
            }
            da += __shfl_xor(da, 1, 4);
            da += __shfl_xor(da, 2, 4);
            if (q == 0) da_s[m][d] = da;
        }
        __syncthreads();                     // da_s ready

        // ---- all m: daWd partial (k in [q*32, q*32+32)) ----
        #pragma unroll
        for (int m = 0; m < MM; ++m) {
            float dw = 0.0f;
            const float4* c4 = (const float4*)(&da_s[m][q * 32]);
            #pragma unroll
            for (int i = 0; i < 8; ++i) {
                const float4 w = wfd[i], x = c4[i];
                dw = fmaf(w.x, x.x, fmaf(w.y, x.y, fmaf(w.z, x.z, fmaf(w.w, x.w, dw))));
            }
            dw += __shfl_xor(dw, 1, 4);
            dw += __shfl_xor(dw, 2, 4);
            if (q == 0)
                ws_daWd[(b * MM + m) * DD + d] = dw;
        }
    } else if (bk < 48) {
        const int d = t & (DD - 1);
        const int j = t >> 7;            // 0..3
        const int k0 = (bk - 32) * 8;
        #pragma unroll
        for (int l = 0; l < 2; ++l) {
            const int k = k0 + j * 2 + l;
            ws_wnT[k * DD + d] = W_final[(size_t)d * 384 + k];
        }
    } else {
        if (t < DD) {
            const int d = t;
            float vp = 0.0f;
            const float4* w = (const float4*)(W_final + (size_t)d * 384 + DD);
            const float4* p = (const float4*)W_pref;
            #pragma unroll
            for (int k4 = 0; k4 < 32; ++k4) {
                const float4 a = w[k4], bb = p[k4];
                vp = fmaf(a.x, bb.x, fmaf(a.y, bb.y, fmaf(a.z, bb.z, fmaf(a.w, bb.w, vp))));
            }
            ws_vpref[d] = vp;
        }
    }
}

// ---------------------------------------------------------------------------
// k_main: R3's proven fused kernel (RPB=32). Client embeddings -> out_nodes
// + LDS; gemv vs wnT (coalesced, L2-resident); fused expansion epilogue.
// Only change vs R3: dawd/vp loads hoisted into the A->B barrier shadow.
// ---------------------------------------------------------------------------
__global__ __launch_bounds__(256) void k_main(
    const float* __restrict__ locs,      // (B, 1010, 2)
    const float* __restrict__ demand,    // (B, 1, 1010)
    const float* __restrict__ pref,      // (B, 10, 1010)
    const float* __restrict__ W_clients, // (128, 5)
    const float* __restrict__ wnT,       // (128, 128)
    const float* __restrict__ ws_daWd,   // (B, 10, 128)
    const float* __restrict__ ws_vpref,  // (128,)
    float* __restrict__ out_nodes,       // (B, 1010, 128)
    float* __restrict__ out_comb)        // (B, 10, 1010, 128)
{
    const int g = blockIdx.x;
    const int b = blockIdx.y;
    const int t = threadIdx.x;
    const int n0 = g * RPB;

    __shared__ float rows[RPB][DD];      // 16 KB
    __shared__ float feat[RPB][5];
    __shared__ float pref_s[MM][RPB];

    if (t < RPB) {
        const int node = n0 + t;
        if (node < NNODES && node >= MM) {
            const float cx = locs[((size_t)b * NNODES + node) * 2 + 0];
            const float cy = locs[((size_t)b * NNODES + node) * 2 + 1];
            const float d0x = locs[((size_t)b * NNODES + 0) * 2 + 0];
            const float d0y = locs[((size_t)b * NNODES + 0) * 2 + 1];
            const float dx = cx - d0x;
            const float dy = cy - d0y;
            feat[t][0] = cx;
            feat[t][1] = cy;
            feat[t][2] = demand[(size_t)b * NNODES + node] * (1.0f / 40.0f);
            feat[t][3] = sqrtf(fmaf(dx, dx, dy * dy));
            feat[t][4] = atan2f(dy, dx);
        }
    }
    for (int idx = t; idx < MM * RPB; idx += 256) {
        const int mm = idx >> 5;
        const int rr = idx & 31;
        const int node = n0 + rr;
        pref_s[mm][rr] = (node < NNODES)
            ? pref[(size_t)(b * MM + mm) * NNODES + node] : 0.0f;
    }
    __syncthreads();

    // phase A
    {
        const int d = t & (DD - 1);
        const int h = t >> 7;
        const float wc0 = W_clients[d * 5 + 0];
        const float wc1 = W_clients[d * 5 + 1];
        const float wc2 = W_clients[d * 5 + 2];
        const float wc3 = W_clients[d * 5 + 3];
        const float wc4 = W_clients[d * 5 + 4];
        #pragma unroll
        for (int i = 0; i < RPB / 2; ++i) {
            const int r = h * (RPB / 2) + i;
            const int node = n0 + r;
            float val = 0.0f;
            if (node < NNODES) {
                if (node < MM) {
                    val = out_nodes[((size_t)b * NNODES + node) * DD + d];
                } else {
                    val = fmaf(feat[r][0], wc0,
                          fmaf(feat[r][1], wc1,
                          fmaf(feat[r][2], wc2,
                          fmaf(feat[r][3], wc3,
                               feat[r][4] * wc4))));
                    out_nodes[((size_t)b * NNODES + node) * DD + d] = val;
                }
            }
            rows[r][d] = val;
        }
    }

    // hoist epilogue operands into the barrier shadow
    const int c = t & 31;
    const int s = t >> 5;
    const int col = c * 4;
    const float4 vp = *(const float4*)(ws_vpref + col);
    float4 dawd[MM];
    #pragma unroll
    for (int mm = 0; mm < MM; ++mm)
        dawd[mm] = *(const float4*)(ws_daWd + (size_t)(b * MM + mm) * DD + col);

    __syncthreads();

    // phase B: (c -> cols 4c..4c+3, s -> rows 4s..4s+3)
    float4 acc[4];
    #pragma unroll
    for (int j = 0; j < 4; ++j) acc[j] = make_float4(0.f, 0.f, 0.f, 0.f);

    {
        const float* wt = wnT + col;
        #pragma unroll 2
        for (int k4 = 0; k4 < DD / 4; ++k4) {
            const float4 w0 = *(const float4*)(wt + (size_t)(k4 * 4 + 0) * DD);
            const float4 w1 = *(const float4*)(wt + (size_t)(k4 * 4 + 1) * DD);
            const float4 w2 = *(const float4*)(wt + (size_t)(k4 * 4 + 2) * DD);
            const float4 w3 = *(const float4*)(wt + (size_t)(k4 * 4 + 3) * DD);
            #pragma unroll
            for (int j = 0; j < 4; ++j) {
                const float4 x = *(const float4*)&rows[s * 4 + j][k4 * 4];
                acc[j].x = fmaf(x.x, w0.x, fmaf(x.y, w1.x,
                           fmaf(x.z, w2.x, fmaf(x.w, w3.x, acc[j].x))));
                acc[j].y = fmaf(x.x, w0.y, fmaf(x.y, w1.y,
                           fmaf(x.z, w2.y, fmaf(x.w, w3.y, acc[j].y))));
                acc[j].z = fmaf(x.x, w0.z, fmaf(x.y, w1.z,
                           fmaf(x.z, w2.z, fmaf(x.w, w3.z, acc[j].z))));
                acc[j].w = fmaf(x.x, w0.w, fmaf(x.y, w1.w,
                           fmaf(x.z, w2.w, fmaf(x.w, w3.w, acc[j].w))));
            }
        }
    }

    // phase C: combined = nwn + pref * v_pref + daWd
    #pragma unroll
    for (int mm = 0; mm < MM; ++mm) {
        #pragma unroll
        for (int j = 0; j < 4; ++j) {
            const int node = n0 + s * 4 + j;
            if (node >= NNODES) continue;
            const float pr = pref_s[mm][s * 4 + j];
            float4 o;
            o.x = fmaf(pr, vp.x, acc[j].x + dawd[mm].x);
            o.y = fmaf(pr, vp.y, acc[j].y + dawd[mm].y);
            o.z = fmaf(pr, vp.z, acc[j].z + dawd[mm].z);
            o.w = fmaf(pr, vp.w, acc[j].w + dawd[mm].w);
            *(float4*)(out_comb +
                ((size_t)(b * MM + mm) * NNODES + node) * DD + col) = o;
        }
    }
}

extern "C" void kernel_launch(void* const* d_in, const int* in_sizes, int n_in,
                              void* d_out, int out_size, void* d_ws, size_t ws_size,
                              hipStream_t stream) {
    const float* locs        = (const float*)d_in[0];
    const float* capacity    = (const float*)d_in[1];
    const float* speed       = (const float*)d_in[2];
    const float* demand      = (const float*)d_in[3];
    const float* agents_pref = (const float*)d_in[4];
    // d_in[5] action_mask: only its shape is used by the reference
    const float* W_depot     = (const float*)d_in[6];
    const float* W_posproj   = (const float*)d_in[7];
    const float* alpha       = (const float*)d_in[8];
    const float* W_agents    = (const float*)d_in[9];
    const float* W_da        = (const float*)d_in[10];
    const float* W_clients   = (const float*)d_in[11];
    const float* W_pref      = (const float*)d_in[12];
    const float* W_final     = (const float*)d_in[13];

    float* out_nodes = (float*)d_out;                         // 32*1010*128
    float* out_comb  = out_nodes + (size_t)BB * NNODES * DD;  // 32*10*1010*128

    float* ws_daWd  = (float*)d_ws;                     // 40960 floats
    float* ws_vpref = ws_daWd + BB * MM * DD;           // 128
    float* ws_wnT   = ws_vpref + DD;                    // 16384

    k_front<<<dim3(49), 512, 0, stream>>>(
        locs, capacity, speed, W_depot, W_posproj, alpha, W_agents,
        W_da, W_pref, W_final, out_nodes, ws_daWd, ws_wnT, ws_vpref);

    k_main<<<dim3(NG, BB), 256, 0, stream>>>(
        locs, demand, agents_pref, W_clients, ws_wnT,
        ws_daWd, ws_vpref, out_nodes, out_comb);
}

// Round 9
// 232.293 us; speedup vs baseline: 1.1760x; 1.0763x over previous
//
#include <hip/hip_runtime.h>
#include <math.h>

#define BB 32
#define MM 10
#define NNODES 1010
#define DD 128
#define RPB 32                          // node rows per tile in k_main
#define NG 32                           // ceil(1010/32)

// ---------------------------------------------------------------------------
// Prep kernel (43 blocks x 256 thr) — verbatim R3 (measured best):
//   blocks  0..15 : WnT[k][d] = W_final[d][k],  WdT[k][d] = W_final[d][256+k]
//   blocks 16..31 : W_daT[k][d] = W_da[d][k]
//   block  32     : v_pref[d] = dot(W_final[d,128:256], W_pref)
//   blocks 33..42 : peproj[m][d] = dot(pe[m,:], W_posproj[d,:])
// ---------------------------------------------------------------------------
__global__ __launch_bounds__(256) void k_prep(
    const float* __restrict__ W_posproj, // (128,128)
    const float* __restrict__ W_da,      // (128,256)
    const float* __restrict__ W_pref,    // (128,1)
    const float* __restrict__ W_final,   // (128,384)
    float* __restrict__ wnT,             // (128,128)
    float* __restrict__ wdT,             // (128,128)
    float* __restrict__ wdaT,            // (256,128)
    float* __restrict__ vpref,           // (128,)
    float* __restrict__ peproj)          // (10,128)
{
    const int bk = blockIdx.x;
    const int t = threadIdx.x;
    const int d = t & (DD - 1);
    const int h = t >> 7;   // 0/1

    if (bk < 16) {
        #pragma unroll
        for (int kk = 0; kk < 4; ++kk) {
            const int k = bk * 8 + h * 4 + kk;
            wnT[k * DD + d] = W_final[(size_t)d * 384 + k];
            wdT[k * DD + d] = W_final[(size_t)d * 384 + 256 + k];
        }
    } else if (bk < 32) {
        #pragma unroll
        for (int kk = 0; kk < 8; ++kk) {
            const int k = (bk - 16) * 16 + h * 8 + kk;
            wdaT[k * DD + d] = W_da[(size_t)d * 256 + k];
        }
    } else if (bk == 32) {
        if (t < DD) {
            float vp = 0.0f;
            const float4* w = (const float4*)(W_final + (size_t)d * 384 + DD);
            const float4* p = (const float4*)W_pref;
            #pragma unroll
            for (int k4 = 0; k4 < 32; ++k4) {
                const float4 a = w[k4], b = p[k4];
                vp = fmaf(a.x, b.x, fmaf(a.y, b.y, fmaf(a.z, b.z, fmaf(a.w, b.w, vp))));
            }
            vpref[d] = vp;
        }
    } else {
        const int m = bk - 33;
        __shared__ float pe_s[DD];
        if (t < DD) {
            const int i = d >> 1;
            const float div = expf((float)(2 * i) * (-logf(10000.0f) / (float)DD));
            const float ang = (float)m * div;
            pe_s[d] = (d & 1) ? cosf(ang) : sinf(ang);
        }
        __syncthreads();
        if (t < DD) {
            float pp = 0.0f;
            const float4* w = (const float4*)(W_posproj + (size_t)d * DD);
            const float4* p = (const float4*)pe_s;
            #pragma unroll
            for (int k4 = 0; k4 < 32; ++k4) {
                const float4 a = w[k4], b = p[k4];
                pp = fmaf(a.x, b.x, fmaf(a.y, b.y, fmaf(a.z, b.z, fmaf(a.w, b.w, pp))));
            }
            peproj[m * DD + d] = pp;
        }
    }
}

// ---------------------------------------------------------------------------
// Agents kernel — verbatim R3 (measured best): per-(b,m), broadcast-gemv on
// transposed W, 256 thr, K split via h.
// ---------------------------------------------------------------------------
__global__ __launch_bounds__(256) void k_agents(
    const float* __restrict__ locs,      // (B, 1010, 2)
    const float* __restrict__ capacity,  // (B, 10)
    const float* __restrict__ speed,     // (B, 10)
    const float* __restrict__ W_depot,   // (128, 2)
    const float* __restrict__ alpha,     // (1,)
    const float* __restrict__ W_agents,  // (128, 4)
    const float* __restrict__ wdaT,      // (256, 128)
    const float* __restrict__ wdT,       // (128, 128)
    const float* __restrict__ peproj,    // (10, 128)
    float* __restrict__ out_nodes,       // (B, 1010, 128)
    float* __restrict__ ws_daWd)         // (B, 10, 128)
{
    const int b = blockIdx.x / MM;
    const int m = blockIdx.x % MM;
    const int t = threadIdx.x;
    const int d = t & (DD - 1);
    const int h = t >> 7;

    __shared__ float cat_s[2 * DD];      // [dep | ag]
    __shared__ float da_s[DD];
    __shared__ float part[2][DD];

    if (h == 0) {
        const float lx = locs[((size_t)b * NNODES + m) * 2 + 0];
        const float ly = locs[((size_t)b * NNODES + m) * 2 + 1];
        const float dep = fmaf(lx, W_depot[d * 2 + 0],
                          fmaf(ly, W_depot[d * 2 + 1],
                               alpha[0] * peproj[m * DD + d]));
        const float cap = capacity[b * MM + m] * (1.0f / 40.0f);
        const float spd = speed[b * MM + m];
        const float ag = fmaf(lx, W_agents[d * 4 + 0],
                         fmaf(ly, W_agents[d * 4 + 1],
                         fmaf(cap, W_agents[d * 4 + 2],
                              spd * W_agents[d * 4 + 3])));
        out_nodes[((size_t)b * NNODES + m) * DD + d] = ag;
        cat_s[d] = dep;
        cat_s[DD + d] = ag;
    }
    __syncthreads();

    {
        float a0 = 0.f, a1 = 0.f, a2 = 0.f, a3 = 0.f;
        const float* wp = wdaT + (size_t)(h * DD) * DD + d;
        const float* cp = cat_s + h * DD;
        #pragma unroll 8
        for (int k = 0; k < DD; k += 4) {
            a0 = fmaf(cp[k + 0], wp[(size_t)(k + 0) * DD], a0);
            a1 = fmaf(cp[k + 1], wp[(size_t)(k + 1) * DD], a1);
            a2 = fmaf(cp[k + 2], wp[(size_t)(k + 2) * DD], a2);
            a3 = fmaf(cp[k + 3], wp[(size_t)(k + 3) * DD], a3);
        }
        part[h][d] = (a0 + a1) + (a2 + a3);
    }
    __syncthreads();
    if (h == 0) da_s[d] = part[0][d] + part[1][d];
    __syncthreads();

    {
        float a0 = 0.f, a1 = 0.f, a2 = 0.f, a3 = 0.f;
        const float* wp = wdT + (size_t)(h * 64) * DD + d;
        const float* cp = da_s + h * 64;
        #pragma unroll 4
        for (int k = 0; k < 64; k += 4) {
            a0 = fmaf(cp[k + 0], wp[(size_t)(k + 0) * DD], a0);
            a1 = fmaf(cp[k + 1], wp[(size_t)(k + 1) * DD], a1);
            a2 = fmaf(cp[k + 2], wp[(size_t)(k + 2) * DD], a2);
            a3 = fmaf(cp[k + 3], wp[(size_t)(k + 3) * DD], a3);
        }
        part[h][d] = (a0 + a1) + (a2 + a3);
    }
    __syncthreads();
    if (h == 0)
        ws_daWd[(b * MM + m) * DD + d] = part[0][d] + part[1][d];
}

// ---------------------------------------------------------------------------
// k_main: R3's fused kernel with ONE change — phases B/C software-pipelined
// per thread: gemv rows 0-1 -> their stores -> gemv rows 2-3 (stores drain
// under this compute) -> final stores. W re-read is L1/L2-hot.
// ---------------------------------------------------------------------------
__global__ __launch_bounds__(256) void k_main(
    const float* __restrict__ locs,      // (B, 1010, 2)
    const float* __restrict__ demand,    // (B, 1, 1010)
    const float* __restrict__ pref,      // (B, 10, 1010)
    const float* __restrict__ W_clients, // (128, 5)
    const float* __restrict__ wnT,       // (128, 128)
    const float* __restrict__ ws_daWd,   // (B, 10, 128)
    const float* __restrict__ ws_vpref,  // (128,)
    float* __restrict__ out_nodes,       // (B, 1010, 128)
    float* __restrict__ out_comb)        // (B, 10, 1010, 128)
{
    const int g = blockIdx.x;
    const int b = blockIdx.y;
    const int t = threadIdx.x;
    const int n0 = g * RPB;

    __shared__ float rows[RPB][DD];      // 16 KB
    __shared__ float feat[RPB][5];
    __shared__ float pref_s[MM][RPB];

    if (t < RPB) {
        const int node = n0 + t;
        if (node < NNODES && node >= MM) {
            const float cx = locs[((size_t)b * NNODES + node) * 2 + 0];
            const float cy = locs[((size_t)b * NNODES + node) * 2 + 1];
            const float d0x = locs[((size_t)b * NNODES + 0) * 2 + 0];
            const float d0y = locs[((size_t)b * NNODES + 0) * 2 + 1];
            const float dx = cx - d0x;
            const float dy = cy - d0y;
            feat[t][0] = cx;
            feat[t][1] = cy;
            feat[t][2] = demand[(size_t)b * NNODES + node] * (1.0f / 40.0f);
            feat[t][3] = sqrtf(fmaf(dx, dx, dy * dy));
            feat[t][4] = atan2f(dy, dx);
        }
    }
    for (int idx = t; idx < MM * RPB; idx += 256) {
        const int mm = idx >> 5;
        const int rr = idx & 31;
        const int node = n0 + rr;
        pref_s[mm][rr] = (node < NNODES)
            ? pref[(size_t)(b * MM + mm) * NNODES + node] : 0.0f;
    }
    __syncthreads();

    // phase A
    {
        const int d = t & (DD - 1);
        const int h = t >> 7;
        const float wc0 = W_clients[d * 5 + 0];
        const float wc1 = W_clients[d * 5 + 1];
        const float wc2 = W_clients[d * 5 + 2];
        const float wc3 = W_clients[d * 5 + 3];
        const float wc4 = W_clients[d * 5 + 4];
        #pragma unroll
        for (int i = 0; i < RPB / 2; ++i) {
            const int r = h * (RPB / 2) + i;
            const int node = n0 + r;
            float val = 0.0f;
            if (node < NNODES) {
                if (node < MM) {
                    val = out_nodes[((size_t)b * NNODES + node) * DD + d];
                } else {
                    val = fmaf(feat[r][0], wc0,
                          fmaf(feat[r][1], wc1,
                          fmaf(feat[r][2], wc2,
                          fmaf(feat[r][3], wc3,
                               feat[r][4] * wc4))));
                    out_nodes[((size_t)b * NNODES + node) * DD + d] = val;
                }
            }
            rows[r][d] = val;
        }
    }

    // epilogue operands (needed before first store pass)
    const int c = t & 31;
    const int s = t >> 5;
    const int col = c * 4;
    const float4 vp = *(const float4*)(ws_vpref + col);
    float4 dawd[MM];
    #pragma unroll
    for (int mm = 0; mm < MM; ++mm)
        dawd[mm] = *(const float4*)(ws_daWd + (size_t)(b * MM + mm) * DD + col);

    __syncthreads();

    const float* wt = wnT + col;

    // ---- pass 1: gemv rows s*4+0, s*4+1 ----
    float4 acc0 = make_float4(0.f, 0.f, 0.f, 0.f);
    float4 acc1 = make_float4(0.f, 0.f, 0.f, 0.f);
    #pragma unroll 2
    for (int k4 = 0; k4 < DD / 4; ++k4) {
        const float4 w0 = *(const float4*)(wt + (size_t)(k4 * 4 + 0) * DD);
        const float4 w1 = *(const float4*)(wt + (size_t)(k4 * 4 + 1) * DD);
        const float4 w2 = *(const float4*)(wt + (size_t)(k4 * 4 + 2) * DD);
        const float4 w3 = *(const float4*)(wt + (size_t)(k4 * 4 + 3) * DD);
        {
            const float4 x = *(const float4*)&rows[s * 4 + 0][k4 * 4];
            acc0.x = fmaf(x.x, w0.x, fmaf(x.y, w1.x, fmaf(x.z, w2.x, fmaf(x.w, w3.x, acc0.x))));
            acc0.y = fmaf(x.x, w0.y, fmaf(x.y, w1.y, fmaf(x.z, w2.y, fmaf(x.w, w3.y, acc0.y))));
            acc0.z = fmaf(x.x, w0.z, fmaf(x.y, w1.z, fmaf(x.z, w2.z, fmaf(x.w, w3.z, acc0.z))));
            acc0.w = fmaf(x.x, w0.w, fmaf(x.y, w1.w, fmaf(x.z, w2.w, fmaf(x.w, w3.w, acc0.w))));
        }
        {
            const float4 x = *(const float4*)&rows[s * 4 + 1][k4 * 4];
            acc1.x = fmaf(x.x, w0.x, fmaf(x.y, w1.x, fmaf(x.z, w2.x, fmaf(x.w, w3.x, acc1.x))));
            acc1.y = fmaf(x.x, w0.y, fmaf(x.y, w1.y, fmaf(x.z, w2.y, fmaf(x.w, w3.y, acc1.y))));
            acc1.z = fmaf(x.x, w0.z, fmaf(x.y, w1.z, fmaf(x.z, w2.z, fmaf(x.w, w3.z, acc1.z))));
            acc1.w = fmaf(x.x, w0.w, fmaf(x.y, w1.w, fmaf(x.z, w2.w, fmaf(x.w, w3.w, acc1.w))));
        }
    }

    // ---- store pass 1 (rows s*4+0, s*4+1) ----
    #pragma unroll
    for (int mm = 0; mm < MM; ++mm) {
        const int node0 = n0 + s * 4 + 0;
        const int node1 = n0 + s * 4 + 1;
        if (node0 < NNODES) {
            const float pr = pref_s[mm][s * 4 + 0];
            float4 o;
            o.x = fmaf(pr, vp.x, acc0.x + dawd[mm].x);
            o.y = fmaf(pr, vp.y, acc0.y + dawd[mm].y);
            o.z = fmaf(pr, vp.z, acc0.z + dawd[mm].z);
            o.w = fmaf(pr, vp.w, acc0.w + dawd[mm].w);
            *(float4*)(out_comb + ((size_t)(b * MM + mm) * NNODES + node0) * DD + col) = o;
        }
        if (node1 < NNODES) {
            const float pr = pref_s[mm][s * 4 + 1];
            float4 o;
            o.x = fmaf(pr, vp.x, acc1.x + dawd[mm].x);
            o.y = fmaf(pr, vp.y, acc1.y + dawd[mm].y);
            o.z = fmaf(pr, vp.z, acc1.z + dawd[mm].z);
            o.w = fmaf(pr, vp.w, acc1.w + dawd[mm].w);
            *(float4*)(out_comb + ((size_t)(b * MM + mm) * NNODES + node1) * DD + col) = o;
        }
    }

    // ---- pass 2: gemv rows s*4+2, s*4+3 (stores drain underneath) ----
    float4 acc2 = make_float4(0.f, 0.f, 0.f, 0.f);
    float4 acc3 = make_float4(0.f, 0.f, 0.f, 0.f);
    #pragma unroll 2
    for (int k4 = 0; k4 < DD / 4; ++k4) {
        const float4 w0 = *(const float4*)(wt + (size_t)(k4 * 4 + 0) * DD);
        const float4 w1 = *(const float4*)(wt + (size_t)(k4 * 4 + 1) * DD);
        const float4 w2 = *(const float4*)(wt + (size_t)(k4 * 4 + 2) * DD);
        const float4 w3 = *(const float4*)(wt + (size_t)(k4 * 4 + 3) * DD);
        {
            const float4 x = *(const float4*)&rows[s * 4 + 2][k4 * 4];
            acc2.x = fmaf(x.x, w0.x, fmaf(x.y, w1.x, fmaf(x.z, w2.x, fmaf(x.w, w3.x, acc2.x))));
            acc2.y = fmaf(x.x, w0.y, fmaf(x.y, w1.y, fmaf(x.z, w2.y, fmaf(x.w, w3.y, acc2.y))));
            acc2.z = fmaf(x.x, w0.z, fmaf(x.y, w1.z, fmaf(x.z, w2.z, fmaf(x.w, w3.z, acc2.z))));
            acc2.w = fmaf(x.x, w0.w, fmaf(x.y, w1.w, fmaf(x.z, w2.w, fmaf(x.w, w3.w, acc2.w))));
        }
        {
            const float4 x = *(const float4*)&rows[s * 4 + 3][k4 * 4];
            acc3.x = fmaf(x.x, w0.x, fmaf(x.y, w1.x, fmaf(x.z, w2.x, fmaf(x.w, w3.x, acc3.x))));
            acc3.y = fmaf(x.x, w0.y, fmaf(x.y, w1.y, fmaf(x.z, w2.y, fmaf(x.w, w3.y, acc3.y))));
            acc3.z = fmaf(x.x, w0.z, fmaf(x.y, w1.z, fmaf(x.z, w2.z, fmaf(x.w, w3.z, acc3.z))));
            acc3.w = fmaf(x.x, w0.w, fmaf(x.y, w1.w, fmaf(x.z, w2.w, fmaf(x.w, w3.w, acc3.w))));
        }
    }

    // ---- store pass 2 (rows s*4+2, s*4+3) ----
    #pragma unroll
    for (int mm = 0; mm < MM; ++mm) {
        const int node2 = n0 + s * 4 + 2;
        const int node3 = n0 + s * 4 + 3;
        if (node2 < NNODES) {
            const float pr = pref_s[mm][s * 4 + 2];
            float4 o;
            o.x = fmaf(pr, vp.x, acc2.x + dawd[mm].x);
            o.y = fmaf(pr, vp.y, acc2.y + dawd[mm].y);
            o.z = fmaf(pr, vp.z, acc2.z + dawd[mm].z);
            o.w = fmaf(pr, vp.w, acc2.w + dawd[mm].w);
            *(float4*)(out_comb + ((size_t)(b * MM + mm) * NNODES + node2) * DD + col) = o;
        }
        if (node3 < NNODES) {
            const float pr = pref_s[mm][s * 4 + 3];
            float4 o;
            o.x = fmaf(pr, vp.x, acc3.x + dawd[mm].x);
            o.y = fmaf(pr, vp.y, acc3.y + dawd[mm].y);
            o.z = fmaf(pr, vp.z, acc3.z + dawd[mm].z);
            o.w = fmaf(pr, vp.w, acc3.w + dawd[mm].w);
            *(float4*)(out_comb + ((size_t)(b * MM + mm) * NNODES + node3) * DD + col) = o;
        }
    }
}

extern "C" void kernel_launch(void* const* d_in, const int* in_sizes, int n_in,
                              void* d_out, int out_size, void* d_ws, size_t ws_size,
                              hipStream_t stream) {
    const float* locs        = (const float*)d_in[0];
    const float* capacity    = (const float*)d_in[1];
    const float* speed       = (const float*)d_in[2];
    const float* demand      = (const float*)d_in[3];
    const float* agents_pref = (const float*)d_in[4];
    // d_in[5] action_mask: only its shape is used by the reference
    const float* W_depot     = (const float*)d_in[6];
    const float* W_posproj   = (const float*)d_in[7];
    const float* alpha       = (const float*)d_in[8];
    const float* W_agents    = (const float*)d_in[9];
    const float* W_da        = (const float*)d_in[10];
    const float* W_clients   = (const float*)d_in[11];
    const float* W_pref      = (const float*)d_in[12];
    const float* W_final     = (const float*)d_in[13];

    float* out_nodes = (float*)d_out;                         // 32*1010*128
    float* out_comb  = out_nodes + (size_t)BB * NNODES * DD;  // 32*10*1010*128

    float* ws_daWd  = (float*)d_ws;                     // 40960
    float* ws_vpref = ws_daWd + BB * MM * DD;           // 128
    float* ws_pepj  = ws_vpref + DD;                    // 1280
    float* ws_wnT   = ws_pepj + MM * DD;                // 16384
    float* ws_wdT   = ws_wnT + DD * DD;                 // 16384
    float* ws_wdaT  = ws_wdT + DD * DD;                 // 32768

    k_prep<<<dim3(43), 256, 0, stream>>>(
        W_posproj, W_da, W_pref, W_final,
        ws_wnT, ws_wdT, ws_wdaT, ws_vpref, ws_pepj);

    k_agents<<<dim3(BB * MM), 256, 0, stream>>>(
        locs, capacity, speed, W_depot, alpha, W_agents,
        ws_wdaT, ws_wdT, ws_pepj, out_nodes, ws_daWd);

    k_main<<<dim3(NG, BB), 256, 0, stream>>>(
        locs, demand, agents_pref, W_clients, ws_wnT,
        ws_daWd, ws_vpref, out_nodes, out_comb);
}